// Round 7
// baseline (401.392 us; speedup 1.0000x reference)
//
#include <hip/hip_runtime.h>
#include <hip/hip_bf16.h>
#include <cstddef>

#define NPIX 262144   // 512*512
#define PW 514        // padded width/height
typedef __hip_bfloat16 bf16;
typedef __attribute__((ext_vector_type(8))) short short8;
typedef __attribute__((ext_vector_type(4))) float f32x4;

__device__ inline unsigned short f2bfu(float f){
  __hip_bfloat16 h = __float2bfloat16(f);
  return *(reinterpret_cast<unsigned short*>(&h));
}
__device__ inline float bflo(unsigned u){ return __uint_as_float(u<<16); }
__device__ inline float bfhi(unsigned u){ return __uint_as_float(u & 0xffff0000u); }
// cheap pair pack: round-half-up bf16, low16=a, high16=b (values finite here)
__device__ inline unsigned pack2bf(float a, float b){
  unsigned ua = __float_as_uint(a), ub = __float_as_uint(b);
  return ((ua + 0x8000u) >> 16) | ((ub + 0x8000u) & 0xffff0000u);
}
// async global->LDS 16B DMA (wave-uniform LDS base + lane*16; gptr per-lane)
__device__ inline void dma16(const bf16* g, unsigned short* l){
  __builtin_amdgcn_global_load_lds(
      (const __attribute__((address_space(1))) unsigned int*)g,
      (__attribute__((address_space(3))) unsigned int*)l, 16, 0, 0);
}

// group-norm affine from accumulated stats (8 channels per group, 262144 px)
__device__ inline void computeAB(const float* stats, const float* gamma, const float* beta,
                                 int c, float& A, float& B){
  int g = c >> 3;
  const float invN = 1.f/2097152.f;
  float m = stats[g*2]*invN;
  float v = stats[g*2+1]*invN - m*m;
  float inv = rsqrtf(v + 1e-5f);
  A = inv*gamma[c];
  B = beta[c] - m*A;
}

// ---------------- merged setup: zero init + all 5 weight transforms ----------------
__global__ void setup_kernel(float* out, float* stats, float* pooled,
                             const float* __restrict__ w1, bf16* __restrict__ wT1,
                             const float* __restrict__ w2, bf16* __restrict__ wT2,
                             const float* __restrict__ w3, bf16* __restrict__ wT3,
                             const float* __restrict__ fw1, bf16* __restrict__ wF1T,
                             const float* __restrict__ fw2, bf16* __restrict__ wF2T){
  int b = blockIdx.x;
  if (b < 1025){
    int i = b*256 + threadIdx.x;
    if (i < 262147) out[i] = 0.f;            // grid + log_prob + entropy + value
    if (i < 68)  stats[i]  = 0.f;
    if (i < 128) pooled[i] = 0.f;
    return;
  }
  b -= 1025;
  if (b < 30){   // conv1 weights: [kc5][oc48][kp32], k = tap*16 + c
    int idx = b*256 + threadIdx.x;
    if (idx < 5*48*32){
      int kp = idx & 31; int oc = (idx >> 5) % 48; int kc = idx / (48*32);
      int k = kc*32 + kp;
      int tap = k >> 4, c = k & 15;
      float v = (tap < 9 && c < 14) ? w1[(oc*14 + c)*9 + tap] : 0.f;
      wT1[idx] = __float2bfloat16(v);
    }
    return;
  }
  b -= 30;
  if (b < 216){  // conv2 weights: [tap][cc2][oc96][cp32] (ic 48..63 zero!)
    int idx = b*256 + threadIdx.x;
    if (idx < 9*2*96*32){
      int cp = idx & 31; int rest = idx >> 5;
      int oc = rest % 96; rest /= 96;
      int cc = rest % 2; int tap = rest / 2;
      int ic = cc*32 + cp;
      float v = (ic < 48) ? w2[(oc*48 + ic)*9 + tap] : 0.f;
      wT2[idx] = __float2bfloat16(v);
    }
    return;
  }
  b -= 216;
  if (b < 432){  // conv3 weights: [tap][cc3][oc128][cp32]
    int idx = b*256 + threadIdx.x;
    if (idx < 9*3*128*32){
      int cp = idx & 31; int rest = idx >> 5;
      int oc = rest & 127; rest >>= 7;
      int cc = rest % 3; int tap = rest / 3;
      int ic = cc*32 + cp;
      float v = (ic < 96) ? w3[(oc*96 + ic)*9 + tap] : 0.f;
      wT3[idx] = __float2bfloat16(v);
    }
    return;
  }
  b -= 432;
  if (b < 1152){ // fc1 weights: [kc36][oc256][kp32], k' = rr*128 + ch (tap-major)
    int idx = b*256 + threadIdx.x;
    if (idx < 36*256*32){
      int kp = idx & 31; int oc = (idx >> 5) & 255; int kc = idx >> 13;
      int k2 = kc*32 + kp;
      int rr = k2 >> 7, ch = k2 & 127;
      wF1T[idx] = __float2bfloat16(fw1[(size_t)(ch*9 + rr)*256 + oc]);
    }
    return;
  }
  b -= 1152;
  {              // fc2 weights: [kc8][oc128][kp32]
    int idx = b*256 + threadIdx.x;
    if (idx < 8*128*32){
      int kp = idx & 31; int oc = (idx >> 5) & 127; int kc = idx >> 12;
      wF2T[idx] = __float2bfloat16(fw2[(size_t)(kc*32 + kp)*128 + oc]);
    }
  }
}

// ---------------- conv1 MFMA: 14ch fp32 NCHW -> 48ch raw bf16 padded NHWC, + stats ----------------
__launch_bounds__(256,2)
__global__ void conv1_mfma_kernel(const float* __restrict__ x, const bf16* __restrict__ wT,
                                  const float* __restrict__ bias, bf16* __restrict__ out,
                                  float* __restrict__ stats){
  constexpr int XP = 24;
  __shared__ unsigned short sX[324*XP];
  __shared__ float sStat[96];
  const int tid = threadIdx.x;
  const int lane = tid & 63, wave = tid >> 6;
  const int quad = lane >> 4, l15 = lane & 15;
  const int tileX = (blockIdx.x & 31)*16, tileY = (blockIdx.x >> 5)*16;
  if (tid < 96) sStat[tid] = 0.f;
  for (int p = tid; p < 324; p += 256){ sX[p*XP+14] = 0; sX[p*XP+15] = 0; }
  for (int idx = tid; idx < 14*324; idx += 256){
    int c = idx / 324, p = idx - c*324;
    int r = p / 18, col = p - r*18;
    int gy = tileY + r - 1, gx = tileX + col - 1;
    float v = 0.f;
    if ((unsigned)gy < 512u && (unsigned)gx < 512u) v = x[(size_t)c*NPIX + gy*512 + gx];
    sX[p*XP + c] = f2bfu(v);
  }
  __syncthreads();

  f32x4 acc[3][4];
  #pragma unroll
  for (int t = 0; t < 3; ++t){
    f32x4 bv = *(const f32x4*)(bias + t*16 + quad*4);
    #pragma unroll
    for (int s = 0; s < 4; ++s) acc[t][s] = bv;
  }
  const int pxb = wave*4;
  const int h = quad >> 1, chalf = (quad & 1)*8;
  const int T0[5] = {0,2,4,6,8};
  const int T1[5] = {1,3,5,7,8};
  #pragma unroll
  for (int kc = 0; kc < 5; ++kc){
    short8 a[3];
    #pragma unroll
    for (int t = 0; t < 3; ++t)
      a[t] = *(const short8*)((const unsigned short*)wT + (size_t)(kc*48 + t*16 + l15)*32 + quad*8);
    const int ky = h ? (T1[kc]/3) : (T0[kc]/3);
    const int kx = h ? (T1[kc]%3) : (T0[kc]%3);
    #pragma unroll
    for (int s = 0; s < 4; ++s){
      int py = pxb + s;
      short8 bfr = *(const short8*)(&sX[((py+ky)*18 + l15+kx)*XP + chalf]);
      #pragma unroll
      for (int t = 0; t < 3; ++t)
        acc[t][s] = __builtin_amdgcn_mfma_f32_16x16x32_bf16(a[t], bfr, acc[t][s], 0, 0, 0);
    }
  }
  #pragma unroll
  for (int t = 0; t < 3; ++t){
    #pragma unroll
    for (int r = 0; r < 4; ++r){
      float sv = 0.f, sq = 0.f;
      #pragma unroll
      for (int s = 0; s < 4; ++s){ float v = acc[t][s][r]; sv += v; sq += v*v; }
      #pragma unroll
      for (int m = 1; m < 16; m <<= 1){ sv += __shfl_xor(sv, m); sq += __shfl_xor(sq, m); }
      if (l15 == 0){
        atomicAdd(&sStat[(t*16 + quad*4 + r)*2],   sv);
        atomicAdd(&sStat[(t*16 + quad*4 + r)*2+1], sq);
      }
    }
    #pragma unroll
    for (int s = 0; s < 4; ++s){
      f32x4 v = acc[t][s];
      uint2 pk;
      pk.x = pack2bf(v[0], v[1]);
      pk.y = pack2bf(v[2], v[3]);
      *(uint2*)(out + ((size_t)(tileY+pxb+s+1)*PW + tileX+l15+1)*48 + t*16 + quad*4) = pk;
    }
  }
  __syncthreads();
  if (tid < 12){
    int g = tid >> 1, wsel = tid & 1;
    float v = 0.f;
    #pragma unroll
    for (int j = 0; j < 8; ++j) v += sStat[(g*8+j)*2 + wsel];
    atomicAdd(&stats[g*2 + wsel], v);
  }
}

// ---------------- in-place GN+ReLU (interior) + zero borders; one block per row ----------------
template<int C>
__global__ void norm_kernel(bf16* buf, const float* __restrict__ stats,
                            const float* __restrict__ gamma, const float* __restrict__ beta){
  __shared__ float sAB[2*C];
  const int tid = threadIdx.x;
  if (tid < C){ float A,B; computeAB(stats, gamma, beta, tid, A, B); sAB[tid]=A; sAB[C+tid]=B; }
  __syncthreads();
  const int y = blockIdx.x;          // 0..513
  uint4* row = (uint4*)(buf + (size_t)y*PW*C);
  constexpr int NU = PW*C/8;         // uint4 per row (C%8==0, no px straddle)
  const bool brow = (y == 0) | (y == 513);
  for (int i = tid; i < NU; i += 256){
    int e = i*8;
    int px = e / C;
    if (brow | (px == 0) | (px == 513)){ row[i] = make_uint4(0,0,0,0); continue; }
    int ch = e - px*C;
    uint4 v = row[i];
    unsigned uu[4] = {v.x,v.y,v.z,v.w}, ou[4];
    #pragma unroll
    for (int j = 0; j < 4; ++j){
      float a = fmaxf(bflo(uu[j])*sAB[ch+j*2]   + sAB[C+ch+j*2],   0.f);
      float d = fmaxf(bfhi(uu[j])*sAB[ch+j*2+1] + sAB[C+ch+j*2+1], 0.f);
      ou[j] = pack2bf(a, d);
    }
    row[i] = make_uint4(ou[0],ou[1],ou[2],ou[3]);
  }
}

// ---------------- MFMA conv: ONE-SHOT full-K DMA staging, one barrier per block ----------------
// LDS slot (cr,row,cc,col) = cr*1296 + (row*4+cc)*18 + col (16B each).
// 4 waves = 2 oc-groups x 2 px-groups; per wave: 2 sequential 4-row halves (acc = OCT*16 AGPR).
template<int IC, int NCC, int OCT, int OC, int MINW>
__launch_bounds__(256, MINW)
__global__ void conv_dma_kernel(const bf16* __restrict__ in, const bf16* __restrict__ wT,
                                const float* __restrict__ bias,
                                bf16* __restrict__ out, float* __restrict__ outstats){
  constexpr int SLOTS = NCC*1296;
  constexpr int NK = (SLOTS + 255)/256;
  __shared__ unsigned short sIn[SLOTS*8];
  __shared__ float sStat[2*OC];
  const int tid  = threadIdx.x;
  const int lane = tid & 63, wave = tid >> 6;
  const int quad = lane >> 4, l15 = lane & 15;
  const int ocg = wave >> 1, pxg = wave & 1;
  const int tileX = (blockIdx.x & 31) * 16, tileY = (blockIdx.x >> 5) * 16;
  const int ocbase = ocg * (OCT*16);

  for (int i = tid; i < 2*OC; i += 256) sStat[i] = 0.f;

  // precompute per-lane DMA source offsets (elements), then issue the whole volley
  unsigned off[NK];
  #pragma unroll
  for (int k = 0; k < NK; ++k){
    int slot = tid + k*256;
    if (slot < SLOTS){
      int cr = slot / 1296; int r2 = slot - cr*1296;
      int row = r2/72; int rem = r2 - row*72;
      int cc = rem/18;  int col = rem - cc*18;
      // for IC=48, chunk 1 cc>=2 reads past-channel (finite) data; weights are 0 there.
      off[k] = (unsigned)(((tileY+row)*PW + tileX+col)*IC + cr*32 + cc*8);
    }
  }
  #pragma unroll
  for (int k = 0; k < NK; ++k){
    int slot = tid + k*256;
    if (slot < SLOTS) dma16(in + off[k], &sIn[slot*8]);
  }
  __syncthreads();               // single drain per block

  #pragma unroll 1
  for (int half = 0; half < 2; ++half){
    f32x4 acc[OCT][4];
    #pragma unroll
    for (int t = 0; t < OCT; ++t){
      f32x4 bv = *(const f32x4*)(bias + ocbase + t*16 + quad*4);
      #pragma unroll
      for (int s = 0; s < 4; ++s) acc[t][s] = bv;
    }
    const int rbase = pxg*8 + half*4;

    #pragma unroll 1
    for (int cr = 0; cr < NCC; ++cr){
      short8 a_cur[OCT], a_nxt[OCT];
      #pragma unroll
      for (int t = 0; t < OCT; ++t)
        a_cur[t] = *(const short8*)((const unsigned short*)wT + ((size_t)(0*NCC + cr)*OC + ocbase + t*16 + l15)*32 + quad*8);
      #pragma unroll
      for (int t = 0; t < OCT; ++t)
        a_nxt[t] = *(const short8*)((const unsigned short*)wT + ((size_t)(1*NCC + cr)*OC + ocbase + t*16 + l15)*32 + quad*8);

      #pragma unroll 1
      for (int tap = 0; tap < 9; ++tap){
        const int ky = tap/3, kx = tap - ky*3;
        short8 b[4];
        #pragma unroll
        for (int s = 0; s < 4; ++s){
          int row = rbase + s + ky;
          b[s] = *(const short8*)(&sIn[(cr*1296 + (row*4 + quad)*18 + l15 + kx)*8]);
        }
        #pragma unroll
        for (int s = 0; s < 4; ++s){
          #pragma unroll
          for (int t = 0; t < OCT; ++t)
            acc[t][s] = __builtin_amdgcn_mfma_f32_16x16x32_bf16(a_cur[t], b[s], acc[t][s], 0, 0, 0);
        }
        #pragma unroll
        for (int t = 0; t < OCT; ++t) a_cur[t] = a_nxt[t];
        if (tap < 7){
          #pragma unroll
          for (int t = 0; t < OCT; ++t)
            a_nxt[t] = *(const short8*)((const unsigned short*)wT + ((size_t)((tap+2)*NCC + cr)*OC + ocbase + t*16 + l15)*32 + quad*8);
        }
      }
    }

    // epilogue for this half: stats + raw bf16 store
    #pragma unroll
    for (int t = 0; t < OCT; ++t){
      #pragma unroll
      for (int r = 0; r < 4; ++r){
        float sv = 0.f, sq = 0.f;
        #pragma unroll
        for (int s = 0; s < 4; ++s){ float v = acc[t][s][r]; sv += v; sq += v*v; }
        #pragma unroll
        for (int m = 1; m < 16; m <<= 1){ sv += __shfl_xor(sv, m); sq += __shfl_xor(sq, m); }
        if (l15 == 0){
          atomicAdd(&sStat[(ocbase + t*16 + quad*4 + r)*2],   sv);
          atomicAdd(&sStat[(ocbase + t*16 + quad*4 + r)*2+1], sq);
        }
      }
      #pragma unroll
      for (int s = 0; s < 4; ++s){
        int py = rbase + s;
        f32x4 v = acc[t][s];
        uint2 pk;
        pk.x = pack2bf(v[0], v[1]);
        pk.y = pack2bf(v[2], v[3]);
        *(uint2*)(out + ((size_t)(tileY+py+1)*PW + (tileX+l15+1))*OC + ocbase + t*16 + quad*4) = pk;
      }
    }
  }
  __syncthreads();
  if (tid < (OC/8)*2){
    int g = tid >> 1, wsel = tid & 1;
    float v = 0.f;
    #pragma unroll
    for (int j = 0; j < 8; ++j) v += sStat[(g*8+j)*2 + wsel];
    atomicAdd(&outstats[g*2 + wsel], v);
  }
}

// ---------------- MEGA: gather+GN+ReLU -> FC1(MFMA) -> FC2(MFMA) -> heads ->
//                  log_prob/entropy/scatter, plus 1 pool row per block. 512 blocks x 16 cells. ----
__launch_bounds__(256)
__global__ void mega_kernel(const bf16* __restrict__ f, const float* __restrict__ instats,
                            const float* __restrict__ gamma, const float* __restrict__ beta,
                            const int* __restrict__ cell_i, const int* __restrict__ cell_j,
                            const int* __restrict__ action,
                            const bf16* __restrict__ wT, const float* __restrict__ fb1,
                            const bf16* __restrict__ wT2, const float* __restrict__ fb2,
                            const float* __restrict__ bw, const float* __restrict__ bb,
                            const float* __restrict__ iw, const float* __restrict__ ib,
                            const float* __restrict__ tw, const float* __restrict__ tb,
                            float* __restrict__ pooled, float* __restrict__ out){
  constexpr int KST = 1160;               // fc1 k stride (shorts)
  __shared__ unsigned short sG[16*KST];   // 37120 B; overlaid by h2L after FC1 reads done
  __shared__ unsigned short h1L[16*264];  // 8448 B
  __shared__ float sAB[256];
  __shared__ int sij[32];
  __shared__ float sRed[2];
  __shared__ float sP[128];
  float* h2L = (float*)sG;                // 16*132 fp32 = 8448 B (inside sG)
  const int tid = threadIdx.x;
  const int lane = tid & 63, wave = tid >> 6;
  const int quad = lane >> 4, l15 = lane & 15;
  const int cb = blockIdx.x*16;

  if (tid < 2) sRed[tid] = 0.f;
  if (tid < 128){ float A,B; computeAB(instats, gamma, beta, tid, A, B);
    sAB[tid]=A; sAB[128+tid]=B; sP[tid]=0.f; }
  if (tid < 16) sij[tid] = cell_i[cb + tid];
  else if (tid < 32) sij[tid] = cell_j[cb + tid - 16];
  __syncthreads();

  // phase 1: gather 16 cells' 3x3x128 patches (GN+ReLU) -> sG [cell][k'=rr*128+ch]
  for (int idx = tid; idx < 16*144; idx += 256){
    int c8 = idx & 15; int t2 = idx >> 4;
    int cell = t2 / 9, rr = t2 - cell*9;
    int r = rr/3, cl = rr - r*3;
    int py = sij[cell] + r, px = sij[16+cell] + cl;   // padded coords
    uint4 v = *(const uint4*)(f + ((size_t)py*PW + px)*128 + c8*8);
    bool border = (py==0) | (py==513) | (px==0) | (px==513);
    unsigned uu[4] = {v.x, v.y, v.z, v.w};
    unsigned ou[4];
    #pragma unroll
    for (int j = 0; j < 4; ++j){
      int ch = c8*8 + j*2;
      float a = border ? 0.f : fmaxf(bflo(uu[j])*sAB[ch]   + sAB[128+ch],   0.f);
      float d = border ? 0.f : fmaxf(bfhi(uu[j])*sAB[ch+1] + sAB[128+ch+1], 0.f);
      ou[j] = pack2bf(a, d);
    }
    uint4 wv; wv.x = ou[0]; wv.y = ou[1]; wv.z = ou[2]; wv.w = ou[3];
    *(uint4*)(&sG[cell*KST + rr*128 + c8*8]) = wv;
  }
  __syncthreads();

  // phase 2: FC1 MFMA (1152 -> 256), wave owns oc [wave*64, wave*64+64)
  {
    f32x4 acc[4];
    const int ocb = wave*64;
    #pragma unroll
    for (int t = 0; t < 4; ++t)
      acc[t] = *(const f32x4*)(fb1 + ocb + t*16 + quad*4);
    #pragma unroll 2
    for (int kc = 0; kc < 36; ++kc){
      short8 b = *(const short8*)(&sG[l15*KST + kc*32 + quad*8]);
      #pragma unroll
      for (int t = 0; t < 4; ++t){
        short8 a = *(const short8*)((const unsigned short*)wT + ((size_t)kc*256 + ocb + t*16 + l15)*32 + quad*8);
        acc[t] = __builtin_amdgcn_mfma_f32_16x16x32_bf16(a, b, acc[t], 0, 0, 0);
      }
    }
    // phase 3: relu -> bf16 -> h1L [cell][oc] stride 264
    #pragma unroll
    for (int t = 0; t < 4; ++t){
      f32x4 v = acc[t];
      uint2 pk;
      pk.x = pack2bf(fmaxf(v[0],0.f), fmaxf(v[1],0.f));
      pk.y = pack2bf(fmaxf(v[2],0.f), fmaxf(v[3],0.f));
      *(uint2*)(&h1L[l15*264 + ocb + t*16 + quad*4]) = pk;
    }
  }
  __syncthreads();

  // phase 4: FC2 MFMA (256 -> 128); wave owns oc [wave*32, wave*32+32)
  {
    const int och = wave*32;
    f32x4 acc2[2];
    #pragma unroll
    for (int t = 0; t < 2; ++t)
      acc2[t] = *(const f32x4*)(fb2 + och + t*16 + quad*4);
    #pragma unroll
    for (int kc = 0; kc < 8; ++kc){
      short8 b = *(const short8*)(&h1L[l15*264 + kc*32 + quad*8]);
      #pragma unroll
      for (int t = 0; t < 2; ++t){
        short8 a = *(const short8*)((const unsigned short*)wT2 + ((size_t)kc*128 + och + t*16 + l15)*32 + quad*8);
        acc2[t] = __builtin_amdgcn_mfma_f32_16x16x32_bf16(a, b, acc2[t], 0, 0, 0);
      }
    }
    // phase 5: relu -> h2L fp32 [cell][oc] stride 132 (overlays sG; sG dead since phase-3 barrier)
    #pragma unroll
    for (int t = 0; t < 2; ++t){
      f32x4 v = acc2[t];
      #pragma unroll
      for (int r = 0; r < 4; ++r) v[r] = fmaxf(v[r], 0.f);
      *(f32x4*)(&h2L[l15*132 + och + t*16 + quad*4]) = v;
    }
  }
  __syncthreads();

  // phase 6: heads (16 cells x 12 outs) + log_prob/entropy/scatter
  if (tid < 192){
    int cell = tid/12, jj = tid - cell*12;
    int which = jj >> 2, o = jj & 3;
    const float* W  = (which==0) ? bw : (which==1 ? iw : tw);
    const float* Bp = (which==0) ? bb : (which==1 ? ib : tb);
    float d = Bp[o];
    const float* h2 = &h2L[cell*132];
    for (int k = 0; k < 128; k++) d += h2[k]*W[k*4+o];
    int cellg = cb + cell;
    if (which == 1){
      out[262147 + cellg*4 + o] = d;
    } else if (which == 2){
      out[262147 + 32768 + cellg*4 + o] = d;
    } else {
      float p = 1.f/(1.f + __expf(-d));
      p = fminf(fmaxf(p, 1e-7f), 1.f - 1e-7f);
      int a = action[cellg*4 + o];
      float lp  = a ? __logf(p) : __logf(1.f-p);
      float ent = -(p*__logf(p) + (1.f-p)*__logf(1.f-p));
      atomicAdd(&sRed[0], lp);
      atomicAdd(&sRed[1], ent);
      if (a){
        const int di[4] = {-1,0,1,0};
        const int dj[4] = {0,1,0,-1};
        int ni = sij[cell] + di[o];
        int nj = sij[16+cell] + dj[o];
        if ((unsigned)ni < 512u && (unsigned)nj < 512u)
          out[ni*512 + nj] = 1.0f;
      }
    }
  }

  // phase 7: global-avg-pool, 1 row per block (512 blocks <-> 512 rows)
  {
    const int gl = tid & 15, xl = tid >> 4;
    float A[8], B[8];
    #pragma unroll
    for (int j = 0; j < 8; ++j){ A[j] = sAB[gl*8+j]; B[j] = sAB[128+gl*8+j]; }
    const int y = blockIdx.x;     // 0..511
    float ps[8] = {0,0,0,0,0,0,0,0};
    for (int x2 = xl; x2 < 512; x2 += 16){
      uint4 v = *(const uint4*)(f + ((size_t)(y+1)*PW + x2+1)*128 + gl*8);
      unsigned uu[4] = {v.x, v.y, v.z, v.w};
      #pragma unroll
      for (int j = 0; j < 4; ++j){
        ps[j*2]   += fmaxf(bflo(uu[j])*A[j*2]   + B[j*2],   0.f);
        ps[j*2+1] += fmaxf(bfhi(uu[j])*A[j*2+1] + B[j*2+1], 0.f);
      }
    }
    #pragma unroll
    for (int j = 0; j < 8; ++j) atomicAdd(&sP[gl*8+j], ps[j]);
  }
  __syncthreads();
  if (tid == 0){
    atomicAdd(&out[262144], sRed[0]);
    atomicAdd(&out[262145], sRed[1]);
  }
  if (tid < 128) atomicAdd(&pooled[tid], sP[tid]);
}

// ---------------- value head MLP ----------------
__global__ void value_kernel(const float* __restrict__ pooled, const float* __restrict__ vw1,
                             const float* __restrict__ vb1, const float* __restrict__ vw2,
                             const float* __restrict__ vb2, float* __restrict__ out){
  int t = threadIdx.x;   // 64 threads
  float h = vb1[t];
  const float invN = 1.f/262144.f;
  for (int c = 0; c < 128; c++) h += (pooled[c]*invN)*vw1[c*64+t];
  h = fmaxf(h, 0.f);
  float v = h*vw2[t];
  #pragma unroll
  for (int off = 32; off; off >>= 1) v += __shfl_xor(v, off);
  if (t == 0) out[262146] = v + vb2[0];
}

extern "C" void kernel_launch(void* const* d_in, const int* in_sizes, int n_in,
                              void* d_out, int out_size, void* d_ws, size_t ws_size,
                              hipStream_t stream) {
  (void)in_sizes; (void)n_in; (void)out_size; (void)ws_size;
  const float* x      = (const float*)d_in[0];
  const int*  cell_i  = (const int*)d_in[1];
  const int*  cell_j  = (const int*)d_in[2];
  const int*  action  = (const int*)d_in[3];
  const float* w1 = (const float*)d_in[4];  const float* b1 = (const float*)d_in[5];
  const float* g1 = (const float*)d_in[6];  const float* be1= (const float*)d_in[7];
  const float* w2 = (const float*)d_in[8];  const float* b2 = (const float*)d_in[9];
  const float* g2 = (const float*)d_in[10]; const float* be2= (const float*)d_in[11];
  const float* w3 = (const float*)d_in[12]; const float* b3 = (const float*)d_in[13];
  const float* g3 = (const float*)d_in[14]; const float* be3= (const float*)d_in[15];
  const float* fw1= (const float*)d_in[16]; const float* fb1= (const float*)d_in[17];
  const float* fw2= (const float*)d_in[18]; const float* fb2= (const float*)d_in[19];
  const float* bw = (const float*)d_in[20]; const float* bb = (const float*)d_in[21];
  const float* iw = (const float*)d_in[22]; const float* ib = (const float*)d_in[23];
  const float* tw = (const float*)d_in[24]; const float* tb = (const float*)d_in[25];
  const float* vw1= (const float*)d_in[26]; const float* vb1= (const float*)d_in[27];
  const float* vw2= (const float*)d_in[28]; const float* vb2= (const float*)d_in[29];

  float* out = (float*)d_out;
  char* ws = (char*)d_ws;
  bf16* buf1 = (bf16*)(ws);                       // 25,362,816 (+small overread slack into buf2)
  bf16* buf2 = (bf16*)(ws + 25362816);            // -> 76,088,448
  bf16* bufF = (bf16*)(ws + 76088448);            // -> 143,722,624
  bf16* wT2  = (bf16*)(ws + 143722624);           // 110,592  -> 143,833,216
  bf16* wT3  = (bf16*)(ws + 143833216);           // 221,184  -> 144,054,400
  bf16* wT1  = (bf16*)(ws + 144054400);           // 15,360   -> 144,069,760
  bf16* wF1T = (bf16*)(ws + 144069760);           // 589,824  -> 144,659,584
  bf16* wF2T = (bf16*)(ws + 144659584);           // 65,536   -> 144,725,120
  float* statsf = (float*)(ws + 144725120);       // 68 floats (L1:0, L2:12, L3:36)
  float* pooled = statsf + 128;                   // 128 floats

  setup_kernel<<<2983, 256, 0, stream>>>(out, statsf, pooled, w1, wT1, w2, wT2, w3, wT3,
                                         fw1, wF1T, fw2, wF2T);
  conv1_mfma_kernel<<<1024, 256, 0, stream>>>(x, wT1, b1, buf1, statsf + 0);
  norm_kernel<48><<<514, 256, 0, stream>>>(buf1, statsf + 0, g1, be1);
  conv_dma_kernel<48,2,3,96,3><<<1024, 256, 0, stream>>>(buf1, wT2, b2, buf2, statsf + 12);
  norm_kernel<96><<<514, 256, 0, stream>>>(buf2, statsf + 12, g2, be2);
  conv_dma_kernel<96,3,4,128,2><<<1024, 256, 0, stream>>>(buf2, wT3, b3, bufF, statsf + 36);
  mega_kernel<<<512, 256, 0, stream>>>(bufF, statsf + 36, g3, be3, cell_i, cell_j, action,
                                       wF1T, fb1, wF2T, fb2, bw, bb, iw, ib, tw, tb,
                                       pooled, out);
  value_kernel<<<1, 64, 0, stream>>>(pooled, vw1, vb1, vw2, vb2, out);
}

// Round 8
// 356.952 us; speedup vs baseline: 1.1245x; 1.1245x over previous
//
#include <hip/hip_runtime.h>
#include <hip/hip_bf16.h>
#include <cstddef>

#define NPIX 262144   // 512*512
#define PW 514        // padded width/height
typedef __hip_bfloat16 bf16;
typedef __attribute__((ext_vector_type(8))) short short8;
typedef __attribute__((ext_vector_type(4))) float f32x4;

__device__ inline unsigned short f2bfu(float f){
  __hip_bfloat16 h = __float2bfloat16(f);
  return *(reinterpret_cast<unsigned short*>(&h));
}
__device__ inline float bflo(unsigned u){ return __uint_as_float(u<<16); }
__device__ inline float bfhi(unsigned u){ return __uint_as_float(u & 0xffff0000u); }
// cheap pair pack: round-half-up bf16, low16=a, high16=b (values finite here)
__device__ inline unsigned pack2bf(float a, float b){
  unsigned ua = __float_as_uint(a), ub = __float_as_uint(b);
  return ((ua + 0x8000u) >> 16) | ((ub + 0x8000u) & 0xffff0000u);
}
// async global->LDS 16B DMA (wave-uniform LDS base + lane*16; gptr per-lane)
__device__ inline void dma16(const bf16* g, unsigned short* l){
  __builtin_amdgcn_global_load_lds(
      (const __attribute__((address_space(1))) unsigned int*)g,
      (__attribute__((address_space(3))) unsigned int*)l, 16, 0, 0);
}

// group-norm affine from accumulated stats (8 channels per group, 262144 px)
__device__ inline void computeAB(const float* stats, const float* gamma, const float* beta,
                                 int c, float& A, float& B){
  int g = c >> 3;
  const float invN = 1.f/2097152.f;
  float m = stats[g*2]*invN;
  float v = stats[g*2+1]*invN - m*m;
  float inv = rsqrtf(v + 1e-5f);
  A = inv*gamma[c];
  B = beta[c] - m*A;
}

// ---------------- merged setup: zero init + all 5 weight transforms ----------------
__global__ void setup_kernel(float* out, float* stats, float* pooled,
                             const float* __restrict__ w1, bf16* __restrict__ wT1,
                             const float* __restrict__ w2, bf16* __restrict__ wT2,
                             const float* __restrict__ w3, bf16* __restrict__ wT3,
                             const float* __restrict__ fw1, bf16* __restrict__ wF1T,
                             const float* __restrict__ fw2, bf16* __restrict__ wF2T){
  int b = blockIdx.x;
  if (b < 1025){
    int i = b*256 + threadIdx.x;
    if (i < 262147) out[i] = 0.f;            // grid + log_prob + entropy + value
    if (i < 68)  stats[i]  = 0.f;
    if (i < 128) pooled[i] = 0.f;
    return;
  }
  b -= 1025;
  if (b < 30){   // conv1 weights: [kc5][oc48][kp32], k = tap*16 + c
    int idx = b*256 + threadIdx.x;
    if (idx < 5*48*32){
      int kp = idx & 31; int oc = (idx >> 5) % 48; int kc = idx / (48*32);
      int k = kc*32 + kp;
      int tap = k >> 4, c = k & 15;
      float v = (tap < 9 && c < 14) ? w1[(oc*14 + c)*9 + tap] : 0.f;
      wT1[idx] = __float2bfloat16(v);
    }
    return;
  }
  b -= 30;
  if (b < 216){  // conv2 weights: [tap][cc2][oc96][cp32] (ic 48..63 zero!)
    int idx = b*256 + threadIdx.x;
    if (idx < 9*2*96*32){
      int cp = idx & 31; int rest = idx >> 5;
      int oc = rest % 96; rest /= 96;
      int cc = rest % 2; int tap = rest / 2;
      int ic = cc*32 + cp;
      float v = (ic < 48) ? w2[(oc*48 + ic)*9 + tap] : 0.f;
      wT2[idx] = __float2bfloat16(v);
    }
    return;
  }
  b -= 216;
  if (b < 432){  // conv3 weights: [tap][cc3][oc128][cp32]
    int idx = b*256 + threadIdx.x;
    if (idx < 9*3*128*32){
      int cp = idx & 31; int rest = idx >> 5;
      int oc = rest & 127; rest >>= 7;
      int cc = rest % 3; int tap = rest / 3;
      int ic = cc*32 + cp;
      float v = (ic < 96) ? w3[(oc*96 + ic)*9 + tap] : 0.f;
      wT3[idx] = __float2bfloat16(v);
    }
    return;
  }
  b -= 432;
  if (b < 1152){ // fc1 weights: [kc36][oc256][kp32], k' = rr*128 + ch (tap-major)
    int idx = b*256 + threadIdx.x;
    if (idx < 36*256*32){
      int kp = idx & 31; int oc = (idx >> 5) & 255; int kc = idx >> 13;
      int k2 = kc*32 + kp;
      int rr = k2 >> 7, ch = k2 & 127;
      wF1T[idx] = __float2bfloat16(fw1[(size_t)(ch*9 + rr)*256 + oc]);
    }
    return;
  }
  b -= 1152;
  {              // fc2 weights: [kc8][oc128][kp32]
    int idx = b*256 + threadIdx.x;
    if (idx < 8*128*32){
      int kp = idx & 31; int oc = (idx >> 5) & 127; int kc = idx >> 12;
      wF2T[idx] = __float2bfloat16(fw2[(size_t)(kc*32 + kp)*128 + oc]);
    }
  }
}

// ---------------- conv1 MFMA: 14ch fp32 NCHW -> 48ch raw bf16 padded NHWC, + stats ----------------
__launch_bounds__(256,2)
__global__ void conv1_mfma_kernel(const float* __restrict__ x, const bf16* __restrict__ wT,
                                  const float* __restrict__ bias, bf16* __restrict__ out,
                                  float* __restrict__ stats){
  constexpr int XP = 24;
  __shared__ unsigned short sX[324*XP];
  __shared__ float sStat[96];
  const int tid = threadIdx.x;
  const int lane = tid & 63, wave = tid >> 6;
  const int quad = lane >> 4, l15 = lane & 15;
  const int tileX = (blockIdx.x & 31)*16, tileY = (blockIdx.x >> 5)*16;
  if (tid < 96) sStat[tid] = 0.f;
  for (int p = tid; p < 324; p += 256){ sX[p*XP+14] = 0; sX[p*XP+15] = 0; }
  for (int idx = tid; idx < 14*324; idx += 256){
    int c = idx / 324, p = idx - c*324;
    int r = p / 18, col = p - r*18;
    int gy = tileY + r - 1, gx = tileX + col - 1;
    float v = 0.f;
    if ((unsigned)gy < 512u && (unsigned)gx < 512u) v = x[(size_t)c*NPIX + gy*512 + gx];
    sX[p*XP + c] = f2bfu(v);
  }
  __syncthreads();

  f32x4 acc[3][4];
  #pragma unroll
  for (int t = 0; t < 3; ++t){
    f32x4 bv = *(const f32x4*)(bias + t*16 + quad*4);
    #pragma unroll
    for (int s = 0; s < 4; ++s) acc[t][s] = bv;
  }
  const int pxb = wave*4;
  const int h = quad >> 1, chalf = (quad & 1)*8;
  const int T0[5] = {0,2,4,6,8};
  const int T1[5] = {1,3,5,7,8};
  #pragma unroll
  for (int kc = 0; kc < 5; ++kc){
    short8 a[3];
    #pragma unroll
    for (int t = 0; t < 3; ++t)
      a[t] = *(const short8*)((const unsigned short*)wT + (size_t)(kc*48 + t*16 + l15)*32 + quad*8);
    const int ky = h ? (T1[kc]/3) : (T0[kc]/3);
    const int kx = h ? (T1[kc]%3) : (T0[kc]%3);
    #pragma unroll
    for (int s = 0; s < 4; ++s){
      int py = pxb + s;
      short8 bfr = *(const short8*)(&sX[((py+ky)*18 + l15+kx)*XP + chalf]);
      #pragma unroll
      for (int t = 0; t < 3; ++t)
        acc[t][s] = __builtin_amdgcn_mfma_f32_16x16x32_bf16(a[t], bfr, acc[t][s], 0, 0, 0);
    }
  }
  #pragma unroll
  for (int t = 0; t < 3; ++t){
    #pragma unroll
    for (int r = 0; r < 4; ++r){
      float sv = 0.f, sq = 0.f;
      #pragma unroll
      for (int s = 0; s < 4; ++s){ float v = acc[t][s][r]; sv += v; sq += v*v; }
      #pragma unroll
      for (int m = 1; m < 16; m <<= 1){ sv += __shfl_xor(sv, m); sq += __shfl_xor(sq, m); }
      if (l15 == 0){
        atomicAdd(&sStat[(t*16 + quad*4 + r)*2],   sv);
        atomicAdd(&sStat[(t*16 + quad*4 + r)*2+1], sq);
      }
    }
    #pragma unroll
    for (int s = 0; s < 4; ++s){
      f32x4 v = acc[t][s];
      uint2 pk;
      pk.x = pack2bf(v[0], v[1]);
      pk.y = pack2bf(v[2], v[3]);
      *(uint2*)(out + ((size_t)(tileY+pxb+s+1)*PW + tileX+l15+1)*48 + t*16 + quad*4) = pk;
    }
  }
  __syncthreads();
  if (tid < 12){
    int g = tid >> 1, wsel = tid & 1;
    float v = 0.f;
    #pragma unroll
    for (int j = 0; j < 8; ++j) v += sStat[(g*8+j)*2 + wsel];
    atomicAdd(&stats[g*2 + wsel], v);
  }
}

// ---------------- in-place GN+ReLU (interior) + zero borders; 4 blocks per row ----------------
template<int C>
__global__ void norm_kernel(bf16* buf, const float* __restrict__ stats,
                            const float* __restrict__ gamma, const float* __restrict__ beta){
  __shared__ float sAB[2*C];
  const int tid = threadIdx.x;
  if (tid < C){ float A,B; computeAB(stats, gamma, beta, tid, A, B); sAB[tid]=A; sAB[C+tid]=B; }
  __syncthreads();
  const int y = blockIdx.x >> 2, q = blockIdx.x & 3;   // y 0..513
  uint4* row = (uint4*)(buf + (size_t)y*PW*C);
  constexpr int NU4 = PW*C/8/4;      // per-quarter uint4 count (divisible for C=48,96)
  const bool brow = (y == 0) | (y == 513);
  for (int i = q*NU4 + tid; i < (q+1)*NU4; i += 256){
    int e = i*8;
    int px = e / C;
    if (brow | (px == 0) | (px == 513)){ row[i] = make_uint4(0,0,0,0); continue; }
    int ch = e - px*C;
    uint4 v = row[i];
    unsigned uu[4] = {v.x,v.y,v.z,v.w}, ou[4];
    #pragma unroll
    for (int j = 0; j < 4; ++j){
      float a = fmaxf(bflo(uu[j])*sAB[ch+j*2]   + sAB[C+ch+j*2],   0.f);
      float d = fmaxf(bfhi(uu[j])*sAB[ch+j*2+1] + sAB[C+ch+j*2+1], 0.f);
      ou[j] = pack2bf(a, d);
    }
    row[i] = make_uint4(ou[0],ou[1],ou[2],ou[3]);
  }
}

// ---------------- MFMA conv, double-buffered DMA, FULLY-UNROLLED tap loop ----------------
// LDS slot (row,cc,col) = (row*4+cc)*18 + col (16B each); b-frag ds_read = one base + imm offset.
template<int IC, int NCC, int OCT, int OC>
__launch_bounds__(256, 2)
__global__ void conv_dma_kernel(const bf16* __restrict__ in, const bf16* __restrict__ wT,
                                const float* __restrict__ bias,
                                bf16* __restrict__ out, float* __restrict__ outstats){
  __shared__ unsigned short sIn[2][1296*8];   // 2 x 20736 B
  __shared__ float sStat[2*OC];
  const int tid  = threadIdx.x;
  const int lane = tid & 63, wave = tid >> 6;
  const int quad = lane >> 4, l15 = lane & 15;
  const int ocg = wave >> 1, pxg = wave & 1;
  const int tileX = (blockIdx.x & 31) * 16, tileY = (blockIdx.x >> 5) * 16;
  const int ocbase = ocg * (OCT*16);

  for (int i = tid; i < 2*OC; i += 256) sStat[i] = 0.f;

  // per-thread DMA source offsets, computed ONCE (chunk adds cr*32 elements)
  unsigned off[6];
  #pragma unroll
  for (int k = 0; k < 6; ++k){
    int slot = tid + k*256;
    if (k < 5 || tid < 16){
      int row = slot/72; int rem = slot - row*72;
      int cc = rem/18;   int col = rem - cc*18;
      // for IC=48, chunk 1 cc>=2 reads past-channel (finite) data; weights are 0 there.
      off[k] = (unsigned)(((tileY+row)*PW + tileX+col)*IC + cc*8);
    }
  }
  auto issueDMA = [&](int cr, int bi){
    #pragma unroll
    for (int k = 0; k < 6; ++k){
      if (k == 5 && tid >= 16) continue;
      dma16(in + off[k] + cr*32, &sIn[bi][(tid + k*256)*8]);
    }
  };

  f32x4 acc[OCT][8];
  #pragma unroll
  for (int t = 0; t < OCT; ++t){
    f32x4 bv = *(const f32x4*)(bias + ocbase + t*16 + quad*4);
    #pragma unroll
    for (int s = 0; s < 8; ++s) acc[t][s] = bv;
  }

  issueDMA(0, 0);
  __syncthreads();               // drains DMA(0); sStat ready

  #pragma unroll 1
  for (int cr = 0; cr < NCC; ++cr){
    // wave-shared b base: all tap/s offsets are compile-time immediates from here
    const unsigned short* B0 = &sIn[cr & 1][(((pxg*8)*4 + quad)*18 + l15)*8];
    const unsigned short* W0 = (const unsigned short*)wT + ((size_t)cr*OC + ocbase + l15)*32 + quad*8;

    #pragma unroll
    for (int tap = 0; tap < 9; ++tap){
      if (tap == 7 && cr + 1 < NCC) issueDMA(cr + 1, (cr + 1) & 1);
      const int ky = tap/3, kx = tap - ky*3;
      short8 a[OCT];
      #pragma unroll
      for (int t = 0; t < OCT; ++t)
        a[t] = *(const short8*)(W0 + (size_t)tap*(NCC*OC*32) + t*512);
      #pragma unroll
      for (int s = 0; s < 8; ++s){
        short8 b = *(const short8*)(B0 + ((s+ky)*72 + kx)*8);
        #pragma unroll
        for (int t = 0; t < OCT; ++t)
          acc[t][s] = __builtin_amdgcn_mfma_f32_16x16x32_bf16(a[t], b, acc[t][s], 0, 0, 0);
      }
    }
    __syncthreads();             // all waves done with this buffer; next DMA drained
  }

  // stats + store raw bf16
  #pragma unroll
  for (int t = 0; t < OCT; ++t){
    #pragma unroll
    for (int r = 0; r < 4; ++r){
      float sv = 0.f, sq = 0.f;
      #pragma unroll
      for (int s = 0; s < 8; ++s){ float v = acc[t][s][r]; sv += v; sq += v*v; }
      #pragma unroll
      for (int m = 1; m < 16; m <<= 1){ sv += __shfl_xor(sv, m); sq += __shfl_xor(sq, m); }
      if (l15 == 0){
        atomicAdd(&sStat[(ocbase + t*16 + quad*4 + r)*2],   sv);
        atomicAdd(&sStat[(ocbase + t*16 + quad*4 + r)*2+1], sq);
      }
    }
    #pragma unroll
    for (int s = 0; s < 8; ++s){
      int py = pxg*8 + s;
      f32x4 v = acc[t][s];
      uint2 pk;
      pk.x = pack2bf(v[0], v[1]);
      pk.y = pack2bf(v[2], v[3]);
      *(uint2*)(out + ((size_t)(tileY+py+1)*PW + (tileX+l15+1))*OC + ocbase + t*16 + quad*4) = pk;
    }
  }
  __syncthreads();
  if (tid < (OC/8)*2){
    int g = tid >> 1, wsel = tid & 1;
    float v = 0.f;
    #pragma unroll
    for (int j = 0; j < 8; ++j) v += sStat[(g*8+j)*2 + wsel];
    atomicAdd(&outstats[g*2 + wsel], v);
  }
}

// ---------------- MEGA: gather+GN+ReLU -> FC1(MFMA) -> FC2(MFMA) -> heads ->
//                  log_prob/entropy/scatter, plus 1 pool row per block. 512 blocks x 16 cells. ----
__launch_bounds__(256)
__global__ void mega_kernel(const bf16* __restrict__ f, const float* __restrict__ instats,
                            const float* __restrict__ gamma, const float* __restrict__ beta,
                            const int* __restrict__ cell_i, const int* __restrict__ cell_j,
                            const int* __restrict__ action,
                            const bf16* __restrict__ wT, const float* __restrict__ fb1,
                            const bf16* __restrict__ wT2, const float* __restrict__ fb2,
                            const float* __restrict__ bw, const float* __restrict__ bb,
                            const float* __restrict__ iw, const float* __restrict__ ib,
                            const float* __restrict__ tw, const float* __restrict__ tb,
                            float* __restrict__ pooled, float* __restrict__ out){
  constexpr int KST = 1160;               // fc1 k stride (shorts)
  __shared__ unsigned short sG[16*KST];   // 37120 B; overlaid by h2L after FC1 reads done
  __shared__ unsigned short h1L[16*264];  // 8448 B
  __shared__ float sAB[256];
  __shared__ int sij[32];
  __shared__ float sRed[2];
  __shared__ float sP[128];
  float* h2L = (float*)sG;                // 16*132 fp32 = 8448 B (inside sG)
  const int tid = threadIdx.x;
  const int lane = tid & 63, wave = tid >> 6;
  const int quad = lane >> 4, l15 = lane & 15;
  const int cb = blockIdx.x*16;

  if (tid < 2) sRed[tid] = 0.f;
  if (tid < 128){ float A,B; computeAB(instats, gamma, beta, tid, A, B);
    sAB[tid]=A; sAB[128+tid]=B; sP[tid]=0.f; }
  if (tid < 16) sij[tid] = cell_i[cb + tid];
  else if (tid < 32) sij[tid] = cell_j[cb + tid - 16];
  __syncthreads();

  // phase 1: gather 16 cells' 3x3x128 patches (GN+ReLU) -> sG [cell][k'=rr*128+ch]
  for (int idx = tid; idx < 16*144; idx += 256){
    int c8 = idx & 15; int t2 = idx >> 4;
    int cell = t2 / 9, rr = t2 - cell*9;
    int r = rr/3, cl = rr - r*3;
    int py = sij[cell] + r, px = sij[16+cell] + cl;   // padded coords
    uint4 v = *(const uint4*)(f + ((size_t)py*PW + px)*128 + c8*8);
    bool border = (py==0) | (py==513) | (px==0) | (px==513);
    unsigned uu[4] = {v.x, v.y, v.z, v.w};
    unsigned ou[4];
    #pragma unroll
    for (int j = 0; j < 4; ++j){
      int ch = c8*8 + j*2;
      float a = border ? 0.f : fmaxf(bflo(uu[j])*sAB[ch]   + sAB[128+ch],   0.f);
      float d = border ? 0.f : fmaxf(bfhi(uu[j])*sAB[ch+1] + sAB[128+ch+1], 0.f);
      ou[j] = pack2bf(a, d);
    }
    uint4 wv; wv.x = ou[0]; wv.y = ou[1]; wv.z = ou[2]; wv.w = ou[3];
    *(uint4*)(&sG[cell*KST + rr*128 + c8*8]) = wv;
  }
  __syncthreads();

  // phase 2: FC1 MFMA (1152 -> 256), wave owns oc [wave*64, wave*64+64)
  {
    f32x4 acc[4];
    const int ocb = wave*64;
    #pragma unroll
    for (int t = 0; t < 4; ++t)
      acc[t] = *(const f32x4*)(fb1 + ocb + t*16 + quad*4);
    #pragma unroll 2
    for (int kc = 0; kc < 36; ++kc){
      short8 b = *(const short8*)(&sG[l15*KST + kc*32 + quad*8]);
      #pragma unroll
      for (int t = 0; t < 4; ++t){
        short8 a = *(const short8*)((const unsigned short*)wT + ((size_t)kc*256 + ocb + t*16 + l15)*32 + quad*8);
        acc[t] = __builtin_amdgcn_mfma_f32_16x16x32_bf16(a, b, acc[t], 0, 0, 0);
      }
    }
    // phase 3: relu -> bf16 -> h1L [cell][oc] stride 264
    #pragma unroll
    for (int t = 0; t < 4; ++t){
      f32x4 v = acc[t];
      uint2 pk;
      pk.x = pack2bf(fmaxf(v[0],0.f), fmaxf(v[1],0.f));
      pk.y = pack2bf(fmaxf(v[2],0.f), fmaxf(v[3],0.f));
      *(uint2*)(&h1L[l15*264 + ocb + t*16 + quad*4]) = pk;
    }
  }
  __syncthreads();

  // phase 4: FC2 MFMA (256 -> 128); wave owns oc [wave*32, wave*32+32)
  {
    const int och = wave*32;
    f32x4 acc2[2];
    #pragma unroll
    for (int t = 0; t < 2; ++t)
      acc2[t] = *(const f32x4*)(fb2 + och + t*16 + quad*4);
    #pragma unroll
    for (int kc = 0; kc < 8; ++kc){
      short8 b = *(const short8*)(&h1L[l15*264 + kc*32 + quad*8]);
      #pragma unroll
      for (int t = 0; t < 2; ++t){
        short8 a = *(const short8*)((const unsigned short*)wT2 + ((size_t)kc*128 + och + t*16 + l15)*32 + quad*8);
        acc2[t] = __builtin_amdgcn_mfma_f32_16x16x32_bf16(a, b, acc2[t], 0, 0, 0);
      }
    }
    // phase 5: relu -> h2L fp32 [cell][oc] stride 132 (overlays sG; sG dead since phase-3 barrier)
    #pragma unroll
    for (int t = 0; t < 2; ++t){
      f32x4 v = acc2[t];
      #pragma unroll
      for (int r = 0; r < 4; ++r) v[r] = fmaxf(v[r], 0.f);
      *(f32x4*)(&h2L[l15*132 + och + t*16 + quad*4]) = v;
    }
  }
  __syncthreads();

  // phase 6: heads (16 cells x 12 outs) + log_prob/entropy/scatter
  if (tid < 192){
    int cell = tid/12, jj = tid - cell*12;
    int which = jj >> 2, o = jj & 3;
    const float* W  = (which==0) ? bw : (which==1 ? iw : tw);
    const float* Bp = (which==0) ? bb : (which==1 ? ib : tb);
    float d = Bp[o];
    const float* h2 = &h2L[cell*132];
    for (int k = 0; k < 128; k++) d += h2[k]*W[k*4+o];
    int cellg = cb + cell;
    if (which == 1){
      out[262147 + cellg*4 + o] = d;
    } else if (which == 2){
      out[262147 + 32768 + cellg*4 + o] = d;
    } else {
      float p = 1.f/(1.f + __expf(-d));
      p = fminf(fmaxf(p, 1e-7f), 1.f - 1e-7f);
      int a = action[cellg*4 + o];
      float lp  = a ? __logf(p) : __logf(1.f-p);
      float ent = -(p*__logf(p) + (1.f-p)*__logf(1.f-p));
      atomicAdd(&sRed[0], lp);
      atomicAdd(&sRed[1], ent);
      if (a){
        const int di[4] = {-1,0,1,0};
        const int dj[4] = {0,1,0,-1};
        int ni = sij[cell] + di[o];
        int nj = sij[16+cell] + dj[o];
        if ((unsigned)ni < 512u && (unsigned)nj < 512u)
          out[ni*512 + nj] = 1.0f;
      }
    }
  }

  // phase 7: global-avg-pool, 1 row per block (512 blocks <-> 512 rows)
  {
    const int gl = tid & 15, xl = tid >> 4;
    float A[8], B[8];
    #pragma unroll
    for (int j = 0; j < 8; ++j){ A[j] = sAB[gl*8+j]; B[j] = sAB[128+gl*8+j]; }
    const int y = blockIdx.x;     // 0..511
    float ps[8] = {0,0,0,0,0,0,0,0};
    for (int x2 = xl; x2 < 512; x2 += 16){
      uint4 v = *(const uint4*)(f + ((size_t)(y+1)*PW + x2+1)*128 + gl*8);
      unsigned uu[4] = {v.x, v.y, v.z, v.w};
      #pragma unroll
      for (int j = 0; j < 4; ++j){
        ps[j*2]   += fmaxf(bflo(uu[j])*A[j*2]   + B[j*2],   0.f);
        ps[j*2+1] += fmaxf(bfhi(uu[j])*A[j*2+1] + B[j*2+1], 0.f);
      }
    }
    #pragma unroll
    for (int j = 0; j < 8; ++j) atomicAdd(&sP[gl*8+j], ps[j]);
  }
  __syncthreads();
  if (tid == 0){
    atomicAdd(&out[262144], sRed[0]);
    atomicAdd(&out[262145], sRed[1]);
  }
  if (tid < 128) atomicAdd(&pooled[tid], sP[tid]);
}

// ---------------- value head MLP ----------------
__global__ void value_kernel(const float* __restrict__ pooled, const float* __restrict__ vw1,
                             const float* __restrict__ vb1, const float* __restrict__ vw2,
                             const float* __restrict__ vb2, float* __restrict__ out){
  int t = threadIdx.x;   // 64 threads
  float h = vb1[t];
  const float invN = 1.f/262144.f;
  for (int c = 0; c < 128; c++) h += (pooled[c]*invN)*vw1[c*64+t];
  h = fmaxf(h, 0.f);
  float v = h*vw2[t];
  #pragma unroll
  for (int off = 32; off; off >>= 1) v += __shfl_xor(v, off);
  if (t == 0) out[262146] = v + vb2[0];
}

extern "C" void kernel_launch(void* const* d_in, const int* in_sizes, int n_in,
                              void* d_out, int out_size, void* d_ws, size_t ws_size,
                              hipStream_t stream) {
  (void)in_sizes; (void)n_in; (void)out_size; (void)ws_size;
  const float* x      = (const float*)d_in[0];
  const int*  cell_i  = (const int*)d_in[1];
  const int*  cell_j  = (const int*)d_in[2];
  const int*  action  = (const int*)d_in[3];
  const float* w1 = (const float*)d_in[4];  const float* b1 = (const float*)d_in[5];
  const float* g1 = (const float*)d_in[6];  const float* be1= (const float*)d_in[7];
  const float* w2 = (const float*)d_in[8];  const float* b2 = (const float*)d_in[9];
  const float* g2 = (const float*)d_in[10]; const float* be2= (const float*)d_in[11];
  const float* w3 = (const float*)d_in[12]; const float* b3 = (const float*)d_in[13];
  const float* g3 = (const float*)d_in[14]; const float* be3= (const float*)d_in[15];
  const float* fw1= (const float*)d_in[16]; const float* fb1= (const float*)d_in[17];
  const float* fw2= (const float*)d_in[18]; const float* fb2= (const float*)d_in[19];
  const float* bw = (const float*)d_in[20]; const float* bb = (const float*)d_in[21];
  const float* iw = (const float*)d_in[22]; const float* ib = (const float*)d_in[23];
  const float* tw = (const float*)d_in[24]; const float* tb = (const float*)d_in[25];
  const float* vw1= (const float*)d_in[26]; const float* vb1= (const float*)d_in[27];
  const float* vw2= (const float*)d_in[28]; const float* vb2= (const float*)d_in[29];

  float* out = (float*)d_out;
  char* ws = (char*)d_ws;
  bf16* buf1 = (bf16*)(ws);                       // 25,362,816 (+small overread slack into buf2)
  bf16* buf2 = (bf16*)(ws + 25362816);            // -> 76,088,448
  bf16* bufF = (bf16*)(ws + 76088448);            // -> 143,722,624
  bf16* wT2  = (bf16*)(ws + 143722624);           // 110,592  -> 143,833,216
  bf16* wT3  = (bf16*)(ws + 143833216);           // 221,184  -> 144,054,400
  bf16* wT1  = (bf16*)(ws + 144054400);           // 15,360   -> 144,069,760
  bf16* wF1T = (bf16*)(ws + 144069760);           // 589,824  -> 144,659,584
  bf16* wF2T = (bf16*)(ws + 144659584);           // 65,536   -> 144,725,120
  float* statsf = (float*)(ws + 144725120);       // 68 floats (L1:0, L2:12, L3:36)
  float* pooled = statsf + 128;                   // 128 floats

  setup_kernel<<<2983, 256, 0, stream>>>(out, statsf, pooled, w1, wT1, w2, wT2, w3, wT3,
                                         fw1, wF1T, fw2, wF2T);
  conv1_mfma_kernel<<<1024, 256, 0, stream>>>(x, wT1, b1, buf1, statsf + 0);
  norm_kernel<48><<<514*4, 256, 0, stream>>>(buf1, statsf + 0, g1, be1);
  conv_dma_kernel<48,2,3,96><<<1024, 256, 0, stream>>>(buf1, wT2, b2, buf2, statsf + 12);
  norm_kernel<96><<<514*4, 256, 0, stream>>>(buf2, statsf + 12, g2, be2);
  conv_dma_kernel<96,3,4,128><<<1024, 256, 0, stream>>>(buf2, wT3, b3, bufF, statsf + 36);
  mega_kernel<<<512, 256, 0, stream>>>(bufF, statsf + 36, g3, be3, cell_i, cell_j, action,
                                       wF1T, fb1, wF2T, fb2, bw, bb, iw, ib, tw, tb,
                                       pooled, out);
  value_kernel<<<1, 64, 0, stream>>>(pooled, vw1, vb1, vw2, vb2, out);
}